// Round 9
// baseline (945341.016 us; speedup 1.0000x reference)
//
#include <hip/hip_runtime.h>

// MultilayerGRU: B=64 S=512 I=128 H=1024 L=3 O=128. FP32 inputs.
//
// R9: R8's independent naive kernel with ONE change: output stored as FP32.
// Five implementations (MFMA wavefront, VALU wavefront, kernel-per-phase,
// naive LDS-sequential) produced bit-identical absmax 0.97216796875 while
// writing bf16. New theory: d_out is FP32 (the reference is pure fp32 JAX and
// the harness doc says d_out matches the reference's output dtype; the bf16
// decode lines in the traceback are pytest source context, not the executed
// branch). Under that theory my bf16 writes decoded as value-at-wrong-index
// pairs + aliased hidden-state + zero tail -> predicted absmax ~0.8-1.0,
// matching 0.972 with the COMPUTATION having been correct since R6.
// This round is both the fix and a decisive probe: if out were bf16 instead,
// fp32 stores decode as bf16-pairs with mantissa-garbage low halves ->
// absmax huge/NaN (distinctive; 0.972 cannot recur).
//
// Design: one WG per batch element (64 WGs x 256 threads), h-state in LDS,
// sequential over t and l. No workspace, no inter-WG communication.

namespace {
constexpr int kB = 64, kS = 512, kI = 128, kH = 1024, kO = 128;
}

__global__ __launch_bounds__(256) void gru_naive(
    const float* __restrict__ X, const float* __restrict__ Wx0,
    const float* __restrict__ Wh0, const float* __restrict__ bh0,
    const float* __restrict__ Wxr, const float* __restrict__ Whr,
    const float* __restrict__ bhr, const float* __restrict__ Wout,
    const float* __restrict__ bout, float* __restrict__ out) {
  __shared__ float hS[3][kH];   // per-layer hidden state
  __shared__ float xS[kI];      // staged x_t (layer 0 input)
  __shared__ float zS[kH], rS[kH], gxS[kH], hnS[kH];

  const int b = blockIdx.x, tid = threadIdx.x;

  for (int c = 0; c < 4; ++c) {
    const int n = tid + c * 256;
    hS[0][n] = 0.f; hS[1][n] = 0.f; hS[2][n] = 0.f;
  }
  __syncthreads();

  for (int t = 0; t < kS; ++t) {
    if (tid < kI) xS[tid] = X[((size_t)b * kS + t) * kI + tid];
    __syncthreads();

    for (int l = 0; l < 3; ++l) {
      const int K = (l == 0) ? kI : kH;
      const float* xin = (l == 0) ? xS : hS[l - 1];
      const float* Wx = (l == 0) ? Wx0 : Wxr + (size_t)(l - 1) * 3 * kH * kH;
      const float* Wh = (l == 0) ? Wh0 : Whr + (size_t)(l - 1) * 3 * kH * kH;
      const float* bb = (l == 0) ? bh0 : bhr + (size_t)(l - 1) * 3 * kH;
      const size_t sx = (size_t)kH * K;   // per-gate stride in Wx
      const size_t sh = (size_t)kH * kH;  // per-gate stride in Wh

      // z, r pre-acts and gx (g's x-part + bias)
      for (int c = 0; c < 4; ++c) {
        const int n = tid + c * 256;
        float az = bb[0 * kH + n], ar = bb[1 * kH + n], ag = bb[2 * kH + n];
        const float* wxz = Wx + 0 * sx + (size_t)n * K;
        const float* wxr = Wx + 1 * sx + (size_t)n * K;
        const float* wxg = Wx + 2 * sx + (size_t)n * K;
        for (int k = 0; k < K; k += 4) {
          const float4 wz = *(const float4*)(wxz + k);
          const float4 wr = *(const float4*)(wxr + k);
          const float4 wg = *(const float4*)(wxg + k);
          const float x0 = xin[k], x1 = xin[k + 1], x2 = xin[k + 2], x3 = xin[k + 3];
          az += x0 * wz.x + x1 * wz.y + x2 * wz.z + x3 * wz.w;
          ar += x0 * wr.x + x1 * wr.y + x2 * wr.z + x3 * wr.w;
          ag += x0 * wg.x + x1 * wg.y + x2 * wg.z + x3 * wg.w;
        }
        const float* whz = Wh + 0 * sh + (size_t)n * kH;
        const float* whr = Wh + 1 * sh + (size_t)n * kH;
        for (int k = 0; k < kH; k += 4) {
          const float4 wz = *(const float4*)(whz + k);
          const float4 wr = *(const float4*)(whr + k);
          const float h0 = hS[l][k], h1 = hS[l][k + 1], h2 = hS[l][k + 2], h3 = hS[l][k + 3];
          az += h0 * wz.x + h1 * wz.y + h2 * wz.z + h3 * wz.w;
          ar += h0 * wr.x + h1 * wr.y + h2 * wr.z + h3 * wr.w;
        }
        zS[n] = 1.f / (1.f + expf(-az));
        rS[n] = 1.f / (1.f + expf(-ar));
        gxS[n] = ag;
      }
      __syncthreads();
      for (int c = 0; c < 4; ++c) {
        const int n = tid + c * 256;
        rS[n] *= hS[l][n];  // r * h_{t-1}
      }
      __syncthreads();
      for (int c = 0; c < 4; ++c) {
        const int n = tid + c * 256;
        float ag = gxS[n];
        const float* whg = Wh + 2 * sh + (size_t)n * kH;
        for (int k = 0; k < kH; k += 4) {
          const float4 wg = *(const float4*)(whg + k);
          ag += rS[k] * wg.x + rS[k + 1] * wg.y + rS[k + 2] * wg.z + rS[k + 3] * wg.w;
        }
        const float g = tanhf(ag);
        hnS[n] = zS[n] * hS[l][n] + (1.f - zS[n]) * g;
      }
      __syncthreads();
      for (int c = 0; c < 4; ++c) {
        const int n = tid + c * 256;
        hS[l][n] = hnS[n];
      }
      __syncthreads();
    }

    // y_t = h2 @ Wout^T + bout  (fp32 store)
    if (tid < kO) {
      float y = bout[tid];
      const float* wo = Wout + (size_t)tid * kH;
      for (int k = 0; k < kH; k += 4) {
        const float4 w = *(const float4*)(wo + k);
        y += hS[2][k] * w.x + hS[2][k + 1] * w.y + hS[2][k + 2] * w.z +
             hS[2][k + 3] * w.w;
      }
      out[((size_t)b * kS + t) * kO + tid] = y;
    }
    __syncthreads();
  }

  // hidden_state (B, L, H), fp32
  for (int c = 0; c < 4; ++c) {
    const int n = tid + c * 256;
    for (int l = 0; l < 3; ++l)
      out[(size_t)kB * kS * kO + (size_t)b * 3 * kH + (size_t)l * kH + n] =
          hS[l][n];
  }
}

extern "C" void kernel_launch(void* const* d_in, const int* in_sizes, int n_in,
                              void* d_out, int out_size, void* d_ws, size_t ws_size,
                              hipStream_t stream) {
  const float* X    = (const float*)d_in[0];
  const float* Wx0  = (const float*)d_in[1];
  const float* Wh0  = (const float*)d_in[2];
  const float* bh0  = (const float*)d_in[3];
  const float* Wxr  = (const float*)d_in[4];
  const float* Whr  = (const float*)d_in[5];
  const float* bhr  = (const float*)d_in[6];
  const float* Wout = (const float*)d_in[7];
  const float* bout = (const float*)d_in[8];
  (void)d_ws; (void)ws_size;

  if (n_in != 9 ||
      in_sizes[0] != 64 * 512 * 128 || in_sizes[1] != 3 * 1024 * 128 ||
      in_sizes[2] != 3 * 1024 * 1024 || in_sizes[3] != 3 * 1024 ||
      in_sizes[4] != 2 * 3 * 1024 * 1024 || in_sizes[5] != 2 * 3 * 1024 * 1024 ||
      in_sizes[6] != 2 * 3 * 1024 || in_sizes[7] != 128 * 1024 ||
      in_sizes[8] != 128 || out_size != 64 * 512 * 128 + 64 * 3 * 1024)
    return;  // diagnostic: out stays 0 -> absmax 0.2129

  hipLaunchKernelGGL(gru_naive, dim3(kB), dim3(256), 0, stream,
                     X, Wx0, Wh0, bh0, Wxr, Whr, bhr, Wout, bout, (float*)d_out);
}